// Round 8
// baseline (1002.579 us; speedup 1.0000x reference)
//
// R12: two structural fusions on R11:
//  (A) gemm_ln_k: 128x256 full-row tile GEMM with LayerNorm epilogue
//      (shfl row-reduce + 2KB LDS cross-wave combine). Replaces
//      {fused-gemm, ln_a} and {W2-gemm, ln_b(tanh)} -> 6 to 4 dispatches
//      per layer, kills the tb round-trip (~130MB/layer HBM).
//  (B) trsm fused into panel_k (both 1-WG): Ls staged from LDS Pn via
//      phys_of map, sigma from piv_s; trsm_k kernel + pivg buffer deleted.
//  Everything else byte-identical to R11.
#include <hip/hip_runtime.h>
#include <math.h>
#include <stdint.h>

#define NE 256
#define DD 256
#define NL 2
#define P_TOT 32640          // NE*(NE-1)/2
#define NB 32                // LU panel width
#define NBP 40               // padded panel columns (chunk overrun, never read)
#define NPANEL (NE / NB)
#define NXCD 8

typedef __bf16 bf16x8 __attribute__((ext_vector_type(8)));
typedef float f32x4 __attribute__((ext_vector_type(4)));

__device__ __forceinline__ float bf2f(ushort h) {
    union { unsigned u; float f; } c; c.u = ((unsigned)h) << 16; return c.f;
}
__device__ __forceinline__ ushort f2bf(float f) {
    union { float f; unsigned u; } c; c.f = f;
    unsigned u = c.u;
    return (ushort)((u + 0x7fffu + ((u >> 16) & 1u)) >> 16);
}

#define GLD16(gp, lp) __builtin_amdgcn_global_load_lds( \
    (const __attribute__((address_space(1))) unsigned int*)(uintptr_t)(gp), \
    (__attribute__((address_space(3))) unsigned int*)(uintptr_t)(lp), 16, 0, 0)

// ---------------- small helpers ----------------
__global__ void idx_k(int* __restrict__ ip, int* __restrict__ jp) {
    int i = threadIdx.x;  // 0..255
    int base = i * 255 - (i * (i - 1)) / 2;
    for (int j = i + 1; j < NE; ++j) {
        ip[base + j - i - 1] = i;
        jp[base + j - i - 1] = j;
    }
}

__global__ void zero_k(float* __restrict__ acc) {
    if (threadIdx.x < 8) acc[threadIdx.x] = 0.f;
}

// ---------------- weight prep: Bt[n][k] = W[k][n] in bf16 ----------------
__global__ __launch_bounds__(256) void prep_w_k(
    const float* __restrict__ Wq, const float* __restrict__ Wk, const float* __restrict__ Wv,
    const float* __restrict__ Wo, const float* __restrict__ W1, const float* __restrict__ W2,
    ushort* __restrict__ Wqkv_t, ushort* __restrict__ Woth_t) {
    __shared__ float Ts[32][33];
    int z = blockIdx.z, l = z / 6, m = z % 6;
    const float* src;
    ushort* dst;
    if (m == 0)      { src = Wq + l * 65536; dst = Wqkv_t + (size_t)l * 768 * 256 + 0 * 65536; }
    else if (m == 1) { src = Wk + l * 65536; dst = Wqkv_t + (size_t)l * 768 * 256 + 1 * 65536; }
    else if (m == 2) { src = Wv + l * 65536; dst = Wqkv_t + (size_t)l * 768 * 256 + 2 * 65536; }
    else             { src = (m == 3 ? Wo : m == 4 ? W1 : W2) + l * 65536;
                       dst = Woth_t + (size_t)(l * 3 + (m - 3)) * 65536; }
    int k0 = blockIdx.x * 32, n0 = blockIdx.y * 32;
    int t = threadIdx.x, tr = t >> 5, tc = t & 31;
    for (int i = tr; i < 32; i += 8) Ts[i][tc] = src[(size_t)(k0 + i) * 256 + n0 + tc];
    __syncthreads();
    for (int i = tr; i < 32; i += 8) dst[(size_t)(n0 + i) * 256 + k0 + tc] = f2bf(Ts[tc][i]);
}

__global__ void prep_b_k(const float* __restrict__ bq, const float* __restrict__ bk,
                         const float* __restrict__ bv, float* __restrict__ bqkv) {
    int l = blockIdx.x, t = threadIdx.x;
    bqkv[l * 768 + t] = bq[l * 256 + t];
    bqkv[l * 768 + 256 + t] = bk[l * 256 + t];
    bqkv[l * 768 + 512 + t] = bv[l * 256 + t];
}

// ---------------- fused weight: Wf_t[l][n][d] = bf16( sum_m Wo[l][d][m]*W1[l][m][n] )
__global__ __launch_bounds__(256) void fuse_w_k(
    const float* __restrict__ Wo, const float* __restrict__ W1,
    ushort* __restrict__ Wf_t) {
    __shared__ float WoS[32][33];   // WoS[d][m]
    __shared__ float W1S[32][33];   // W1S[m][n]
    int l = blockIdx.z;
    int n0 = blockIdx.x * 32, d0 = blockIdx.y * 32;
    const float* wo = Wo + l * 65536;
    const float* w1 = W1 + l * 65536;
    int t = threadIdx.x, ty = t >> 5, tx = t & 31;
    float acc4[4] = {0.f, 0.f, 0.f, 0.f};
    for (int m0 = 0; m0 < 256; m0 += 32) {
        __syncthreads();
        for (int i = ty; i < 32; i += 8) {
            WoS[i][tx] = wo[(size_t)(d0 + i) * 256 + m0 + tx];
            W1S[i][tx] = w1[(size_t)(m0 + i) * 256 + n0 + tx];
        }
        __syncthreads();
#pragma unroll
        for (int jm = 0; jm < 32; ++jm) {
            float a = WoS[tx][jm];
#pragma unroll
            for (int q = 0; q < 4; ++q)
                acc4[q] += a * W1S[jm][ty + 8 * q];
        }
    }
#pragma unroll
    for (int q = 0; q < 4; ++q)
        Wf_t[(size_t)l * 65536 + (size_t)(n0 + ty + 8 * q) * 256 + d0 + tx] = f2bf(acc4[q]);
}

// bfuse[l][n] = sum_m bo[l][m]*W1[l][m][n]
__global__ void fuse_b_k(const float* __restrict__ bo, const float* __restrict__ W1,
                         float* __restrict__ bfuse) {
    int l = blockIdx.x, n = threadIdx.x;
    const float* w1 = W1 + l * 65536;
    const float* b = bo + l * 256;
    float s = 0.f;
    for (int m = 0; m < 256; ++m) s += b[m] * w1[(size_t)m * 256 + n];
    bfuse[l * 256 + n] = s;
}

// ---------------- embedding: h = feat @ W_in (bf16 out) ----------------
__global__ __launch_bounds__(256) void embed_k(
    const float* __restrict__ el, const float* __restrict__ Win,
    const int* __restrict__ ip, const int* __restrict__ jp,
    ushort* __restrict__ h, int P0) {
    int w = threadIdx.x >> 6, lane = threadIdx.x & 63;
    int r = blockIdx.x * 4 + w;
    int gp = P0 + (r >> 1);
    int e = (r & 1) ? jp[gp] : ip[gp];
    float th = el[2 * e], ph = el[2 * e + 1];
    float st = sinf(th);
    float f0 = cosf(th), f1 = st * cosf(ph), f2 = st * sinf(ph);
    int n = lane * 4;
    float4 w0 = *(const float4*)&Win[n];
    float4 w1 = *(const float4*)&Win[256 + n];
    float4 w2 = *(const float4*)&Win[512 + n];
    ushort4 o;
    o.x = f2bf(f0 * w0.x + f1 * w1.x + f2 * w2.x);
    o.y = f2bf(f0 * w0.y + f1 * w1.y + f2 * w2.y);
    o.z = f2bf(f0 * w0.z + f1 * w1.z + f2 * w2.z);
    o.w = f2bf(f0 * w0.w + f1 * w1.w + f2 * w2.w);
    *(ushort4*)&h[(size_t)r * 256 + n] = o;
}

// ---------------- bf16 MFMA GEMM: C = A@B (+bias) (+residual) ----------------
// 1D grid, XCD-chunked bijective swizzle (see R10).
template <bool BIAS, bool RES>
__global__ __launch_bounds__(256) void gemm_k(
    const ushort* __restrict__ A, int lda,
    const ushort* __restrict__ Bt,
    const float* __restrict__ bias,
    const ushort* __restrict__ Rm, int ldr,
    ushort* __restrict__ C, int ldc, int ny) {
    __shared__ ushort As[128 * 64];
    __shared__ ushort Bs[128 * 64];
    int t = threadIdx.x, lane = t & 63, w = t >> 6;
    int nwg = gridDim.x;
    int orig = blockIdx.x;
    int qq = nwg / NXCD, rr = nwg % NXCD;
    int xcd = orig % NXCD, idx = orig / NXCD;
    int wg = (xcd < rr ? xcd * (qq + 1) : rr * (qq + 1) + (xcd - rr) * qq) + idx;
    int row0 = (wg / ny) * 128, col0 = (wg % ny) * 128;
    int lrow = lane >> 3;                 // row within 8-row staging chunk
    int kx = ((lane & 7) ^ lrow) << 3;    // swizzled k element offset
    const ushort* gA = A + (size_t)(row0 + w * 32 + lrow) * lda + kx;
    const ushort* gB = Bt + (size_t)(col0 + w * 32 + lrow) * 256 + kx;
    f32x4 acc[4][4];
#pragma unroll
    for (int i = 0; i < 4; ++i)
#pragma unroll
        for (int j = 0; j < 4; ++j) acc[i][j] = (f32x4){0.f, 0.f, 0.f, 0.f};
    int wm = w >> 1, wn = w & 1;
    int mbase = wm * 64 + (lane & 15);
    int nbase = wn * 64 + (lane & 15);
    int l7 = lane & 7;
    for (int k0 = 0; k0 < 256; k0 += 64) {
        __syncthreads();
#pragma unroll
        for (int c2 = 0; c2 < 4; ++c2) {
            GLD16(gA + (size_t)(c2 * 8) * lda + k0, &As[(w * 4 + c2) * 512]);
            GLD16(gB + (size_t)(c2 * 8) * 256 + k0, &Bs[(w * 4 + c2) * 512]);
        }
        __syncthreads();
#pragma unroll
        for (int ks = 0; ks < 2; ++ks) {
            int kb = ks * 4 + (lane >> 4);
            bf16x8 af[4], bfr[4];
#pragma unroll
            for (int tm = 0; tm < 4; ++tm)
                af[tm] = *(const bf16x8*)&As[(mbase + tm * 16) * 64 + ((kb ^ l7) << 3)];
#pragma unroll
            for (int tn = 0; tn < 4; ++tn)
                bfr[tn] = *(const bf16x8*)&Bs[(nbase + tn * 16) * 64 + ((kb ^ l7) << 3)];
#pragma unroll
            for (int tm = 0; tm < 4; ++tm)
#pragma unroll
                for (int tn = 0; tn < 4; ++tn)
                    acc[tm][tn] = __builtin_amdgcn_mfma_f32_16x16x32_bf16(
                        af[tm], bfr[tn], acc[tm][tn], 0, 0, 0);
        }
    }
    int q = lane >> 4;
    int crow = row0 + wm * 64 + q * 4;
    int ccol = col0 + wn * 64 + (lane & 15);
#pragma unroll
    for (int tm = 0; tm < 4; ++tm)
#pragma unroll
        for (int r = 0; r < 4; ++r) {
            int row = crow + tm * 16 + r;
#pragma unroll
            for (int tn = 0; tn < 4; ++tn) {
                int col = ccol + tn * 16;
                float v = acc[tm][tn][r];
                if (BIAS) v += bias[col];
                if (RES) v += bf2f(Rm[(size_t)row * ldr + col]);
                C[(size_t)row * ldc + col] = f2bf(v);
            }
        }
}

// ---------------- GEMM (128x256 full-row tile) + LayerNorm epilogue ----------
// C[row] = LN( x ) with  x = acc + bias (+ res)        (TANH=false)
//                        x = res + tanh(acc + bias)    (TANH=true)
// ny==1: each block owns complete rows -> LN per-row stats are block-local;
// in-place hb update is race-free (block touches only its own rows).
template <bool TANH>
__global__ __launch_bounds__(256) void gemm_ln_k(
    const ushort* __restrict__ A, int lda,
    const ushort* __restrict__ Bt,
    const float* __restrict__ bias,
    const ushort* __restrict__ Rm,            // residual, ld 256
    const float* __restrict__ sc, const float* __restrict__ bi,
    ushort* __restrict__ C) {                 // ld 256
    __shared__ ushort As[128 * 64];           // 16 KB
    __shared__ ushort Bs[256 * 64];           // 32 KB
    __shared__ float red_s[128][2][2];        // [row_local][wn][{sum,sumsq}]
    int t = threadIdx.x, lane = t & 63, w = t >> 6;
    int row0 = blockIdx.x * 128;
    int lrow = lane >> 3;
    int kx = ((lane & 7) ^ lrow) << 3;
    const ushort* gA = A + (size_t)(row0 + w * 32 + lrow) * lda + kx;
    const ushort* gB = Bt + (size_t)(w * 64 + lrow) * 256 + kx;
    f32x4 acc[4][8];
#pragma unroll
    for (int i = 0; i < 4; ++i)
#pragma unroll
        for (int j = 0; j < 8; ++j) acc[i][j] = (f32x4){0.f, 0.f, 0.f, 0.f};
    int wm = w >> 1, wn = w & 1;
    int mbase = wm * 64 + (lane & 15);
    int nbase = wn * 128 + (lane & 15);
    int l7 = lane & 7;
    for (int k0 = 0; k0 < 256; k0 += 64) {
        __syncthreads();
#pragma unroll
        for (int c2 = 0; c2 < 4; ++c2)
            GLD16(gA + (size_t)(c2 * 8) * lda + k0, &As[(w * 4 + c2) * 512]);
#pragma unroll
        for (int c2 = 0; c2 < 8; ++c2)
            GLD16(gB + (size_t)(c2 * 8) * 256 + k0, &Bs[(w * 8 + c2) * 512]);
        __syncthreads();
#pragma unroll
        for (int ks = 0; ks < 2; ++ks) {
            int kb = ks * 4 + (lane >> 4);
            bf16x8 af[4], bfr[8];
#pragma unroll
            for (int tm = 0; tm < 4; ++tm)
                af[tm] = *(const bf16x8*)&As[(mbase + tm * 16) * 64 + ((kb ^ l7) << 3)];
#pragma unroll
            for (int tn = 0; tn < 8; ++tn)
                bfr[tn] = *(const bf16x8*)&Bs[(nbase + tn * 16) * 64 + ((kb ^ l7) << 3)];
#pragma unroll
            for (int tm = 0; tm < 4; ++tm)
#pragma unroll
                for (int tn = 0; tn < 8; ++tn)
                    acc[tm][tn] = __builtin_amdgcn_mfma_f32_16x16x32_bf16(
                        af[tm], bfr[tn], acc[tm][tn], 0, 0, 0);
        }
    }
    int q = lane >> 4;
    // pass 1: x = bias/res/tanh applied (stored back into acc), row partials
#pragma unroll
    for (int tm = 0; tm < 4; ++tm)
#pragma unroll
        for (int r = 0; r < 4; ++r) {
            int rl = wm * 64 + tm * 16 + q * 4 + r;
            int row = row0 + rl;
            float s = 0.f, sq = 0.f;
#pragma unroll
            for (int tn = 0; tn < 8; ++tn) {
                int col = wn * 128 + (lane & 15) + tn * 16;
                float v = acc[tm][tn][r] + bias[col];
                float x;
                if (TANH) x = bf2f(Rm[(size_t)row * 256 + col]) + tanhf(v);
                else      x = v + bf2f(Rm[(size_t)row * 256 + col]);
                acc[tm][tn][r] = x;
                s += x; sq += x * x;
            }
#pragma unroll
            for (int off = 1; off <= 8; off <<= 1) {
                s += __shfl_xor(s, off, 64);
                sq += __shfl_xor(sq, off, 64);
            }
            if ((lane & 15) == 0) { red_s[rl][wn][0] = s; red_s[rl][wn][1] = sq; }
        }
    __syncthreads();
    // pass 2: normalize + affine + store
    float sc8[8], bi8[8];
#pragma unroll
    for (int tn = 0; tn < 8; ++tn) {
        int col = wn * 128 + (lane & 15) + tn * 16;
        sc8[tn] = sc[col]; bi8[tn] = bi[col];
    }
#pragma unroll
    for (int tm = 0; tm < 4; ++tm)
#pragma unroll
        for (int r = 0; r < 4; ++r) {
            int rl = wm * 64 + tm * 16 + q * 4 + r;
            int row = row0 + rl;
            float m = (red_s[rl][0][0] + red_s[rl][1][0]) * (1.f / 256.f);
            float var = (red_s[rl][0][1] + red_s[rl][1][1]) * (1.f / 256.f) - m * m;
            float rs = rsqrtf(var + 1e-5f);
#pragma unroll
            for (int tn = 0; tn < 8; ++tn) {
                int col = wn * 128 + (lane & 15) + tn * 16;
                C[(size_t)row * 256 + col] =
                    f2bf((acc[tm][tn][r] - m) * rs * sc8[tn] + bi8[tn]);
            }
        }
}

// ---------------- attention (seq=2) on fused qkv [row,768] ----------------
__global__ __launch_bounds__(256) void attn_k(ushort* __restrict__ qkv) {
    int wid = threadIdx.x >> 6, lane = threadIdx.x & 63;
    int gw = blockIdx.x * 4 + wid;
    int p = gw >> 2, hh = gw & 3;
    size_t r0 = (size_t)(2 * p) * 768 + hh * 64 + lane;
    size_t r1 = r0 + 768;
    float q0 = bf2f(qkv[r0]) * 0.125f, q1 = bf2f(qkv[r1]) * 0.125f;
    float k0 = bf2f(qkv[r0 + 256]), k1 = bf2f(qkv[r1 + 256]);
    float v0 = bf2f(qkv[r0 + 512]), v1 = bf2f(qkv[r1 + 512]);
    float s00 = q0 * k0, s01 = q0 * k1, s10 = q1 * k0, s11 = q1 * k1;
#pragma unroll
    for (int off = 32; off; off >>= 1) {
        s00 += __shfl_xor(s00, off, 64);
        s01 += __shfl_xor(s01, off, 64);
        s10 += __shfl_xor(s10, off, 64);
        s11 += __shfl_xor(s11, off, 64);
    }
    float m0 = fmaxf(s00, s01), m1 = fmaxf(s10, s11);
    float e00 = expf(s00 - m0), e01 = expf(s01 - m0);
    float e10 = expf(s10 - m1), e11 = expf(s11 - m1);
    float i0 = 1.f / (e00 + e01), i1 = 1.f / (e10 + e11);
    float o0 = (e00 * i0) * v0 + (e01 * i0) * v1;
    float o1 = (e10 * i1) * v0 + (e11 * i1) * v1;
    qkv[r0] = f2bf(o0);
    qkv[r1] = f2bf(o1);
}

// ---------------- per-pair orbitals + 2x2 det ----------------
__global__ __launch_bounds__(256) void orb_k(
    const ushort* __restrict__ h, const float* __restrict__ Wr, const float* __restrict__ Wi,
    const float* __restrict__ el, const int* __restrict__ ip, const int* __restrict__ jp,
    float2* __restrict__ porb, int P0) {
    int w = threadIdx.x >> 6, lane = threadIdx.x & 63;
    int p = blockIdx.x * 4 + w;
    const ushort* h0 = h + (size_t)(2 * p) * 256;
    int d0 = lane * 4;
    ushort4 a0 = *(const ushort4*)&h0[d0];
    ushort4 a1 = *(const ushort4*)&h0[256 + d0];
    float x0[4] = {bf2f(a0.x), bf2f(a0.y), bf2f(a0.z), bf2f(a0.w)};
    float x1[4] = {bf2f(a1.x), bf2f(a1.y), bf2f(a1.z), bf2f(a1.w)};
    float wrv[8], wiv[8];
    *(float4*)&wrv[0] = *(const float4*)&Wr[2 * d0];
    *(float4*)&wrv[4] = *(const float4*)&Wr[2 * d0 + 4];
    *(float4*)&wiv[0] = *(const float4*)&Wi[2 * d0];
    *(float4*)&wiv[4] = *(const float4*)&Wi[2 * d0 + 4];
    float s[8] = {0, 0, 0, 0, 0, 0, 0, 0};
#pragma unroll
    for (int u = 0; u < 4; ++u) {
        s[0] += x0[u] * wrv[2 * u];     s[1] += x0[u] * wiv[2 * u];
        s[2] += x0[u] * wrv[2 * u + 1]; s[3] += x0[u] * wiv[2 * u + 1];
        s[4] += x1[u] * wrv[2 * u];     s[5] += x1[u] * wiv[2 * u];
        s[6] += x1[u] * wrv[2 * u + 1]; s[7] += x1[u] * wiv[2 * u + 1];
    }
#pragma unroll
    for (int off = 32; off; off >>= 1) {
#pragma unroll
        for (int q2 = 0; q2 < 8; ++q2) s[q2] += __shfl_xor(s[q2], off, 64);
    }
    if (lane == 0) {
        int gp = P0 + p;
        int i = ip[gp], j = jp[gp];
        float thi = el[2 * i], phi_ = el[2 * i + 1];
        float thj = el[2 * j], phj = el[2 * j + 1];
        float chi = cosf(thi * 0.5f), shi = sinf(thi * 0.5f);
        float chj = cosf(thj * 0.5f), shj = sinf(thj * 0.5f);
        float cpi = cosf(phi_ * 0.5f), spi = sinf(phi_ * 0.5f);
        float cpj = cosf(phj * 0.5f), spj = sinf(phj * 0.5f);
        float uix = chi * cpi, uiy = chi * spi;
        float vix = shi * cpi, viy = -shi * spi;
        float ujx = chj * cpj, ujy = chj * spj;
        float vjx = shj * cpj, vjy = -shj * spj;
        float crx = (uix * vjx - uiy * vjy) - (ujx * vix - ujy * viy);
        float cry = (uix * vjy + uiy * vjx) - (ujx * viy + ujy * vix);
        float chord2 = crx * crx + cry * cry;
        float trunc = 1.f - expf(-100.f * chord2);
        float t2 = trunc * trunc;
        float dr = (s[0] * s[6] - s[1] * s[7]) - (s[2] * s[4] - s[3] * s[5]);
        float di = (s[0] * s[7] + s[1] * s[6]) - (s[2] * s[5] + s[3] * s[4]);
        porb[gp] = make_float2(dr * t2, di * t2);
    }
}

// ---------------- assemble A = pf + cusp, accumulate log_bos ----------------
__global__ __launch_bounds__(256) void assemble_k(
    const float* __restrict__ el, const float2* __restrict__ porb,
    float2* __restrict__ Am, float* acc) {
    __shared__ float sre[256], sim[256];
    int idx = blockIdx.x * 256 + threadIdx.x;
    int i = idx >> 8, j = idx & 255;
    float thi = el[2 * i], phi_ = el[2 * i + 1];
    float thj = el[2 * j], phj = el[2 * j + 1];
    float chi = cosf(thi * 0.5f), shi = sinf(thi * 0.5f);
    float chj = cosf(thj * 0.5f), shj = sinf(thj * 0.5f);
    float cpi = cosf(phi_ * 0.5f), spi = sinf(phi_ * 0.5f);
    float cpj = cosf(phj * 0.5f), spj = sinf(phj * 0.5f);
    float uix = chi * cpi, uiy = chi * spi;
    float vix = shi * cpi, viy = -shi * spi;
    float ujx = chj * cpj, ujy = chj * spj;
    float vjx = shj * cpj, vjy = -shj * spj;
    float ex = (uix * vjx - uiy * vjy) - (ujx * vix - ujy * viy);
    float ey = (uix * vjy + uiy * vjx) - (ujx * viy + ujy * vix);
    float pfx = 0.f, pfy = 0.f;
    if (i < j) {
        int pp = i * 255 - (i * (i - 1)) / 2 + (j - i - 1);
        float2 t = porb[pp]; pfx = t.x; pfy = t.y;
    } else if (i > j) {
        int pp = j * 255 - (j * (j - 1)) / 2 + (i - j - 1);
        float2 t = porb[pp]; pfx = -t.x; pfy = -t.y;
    }
    float eye = (i == j) ? 1.f : 0.f;
    float ecx = ex + eye, ecy = ey;
    float wgt = expf(-100.f * (ecx * ecx + ecy * ecy));
    Am[idx] = make_float2(pfx + ecx * wgt, pfy + ecy * wgt);
    float lre = 0.f, lim = 0.f;
    if (i != j) {
        float r2 = ex * ex + ey * ey;
        lre = 0.5f * logf(0.01f + r2);
        lim = atan2f(ey, ex);
    }
    sre[threadIdx.x] = lre; sim[threadIdx.x] = lim;
    __syncthreads();
    for (int s2 = 128; s2; s2 >>= 1) {
        if (threadIdx.x < s2) {
            sre[threadIdx.x] += sre[threadIdx.x + s2];
            sim[threadIdx.x] += sim[threadIdx.x + s2];
        }
        __syncthreads();
    }
    if (threadIdx.x == 0) {
        atomicAdd(acc + 0, sre[0]);
        atomicAdd(acc + 1, sim[0]);
    }
}

// ---------------- LU panel v8 + fused trsm ----------------
__device__ __forceinline__ unsigned wave_max_u32_dpp(unsigned m) {
#define DPP_STEP(ctrl) { \
    unsigned tmp_ = (unsigned)__builtin_amdgcn_update_dpp((int)m, (int)m, ctrl, 0xf, 0xf, false); \
    m = (m >= tmp_) ? m : tmp_; }
    DPP_STEP(0x111)  // row_shr:1
    DPP_STEP(0x112)  // row_shr:2
    DPP_STEP(0x114)  // row_shr:4
    DPP_STEP(0x118)  // row_shr:8
    DPP_STEP(0x142)  // row_bcast:15
    DPP_STEP(0x143)  // row_bcast:31
#undef DPP_STEP
    return (unsigned)__builtin_amdgcn_readlane((int)m, 63);
}

__global__ __launch_bounds__(256) void panel_k(
    float2* __restrict__ Am, float* __restrict__ acc, int k0) {
    __shared__ float2 Pn[NBP][NE];                // 80 KB padded transposed panel
    __shared__ alignas(16) unsigned rbest4[2][4]; // parity double-buffered
    __shared__ float2 diag_s[NB];
    __shared__ short piv_s[NB];
    __shared__ short phys_of_s[NB];
    __shared__ float2 Ls[NB][NB + 1];             // fused-trsm L11 stage
    __shared__ short sigma_s[NE];
    __shared__ short rlist_s[NB];
    __shared__ int rcount_s;
    int t = threadIdx.x, lane = t & 63, w = t >> 6;
    int nr = NE - k0;
    bool act = t < nr;
    float2 cur = make_float2(0.f, 0.f);   // own value at current pivot column
    if (act) {
        const float4* src = (const float4*)(Am + (size_t)(k0 + t) * NE + k0);
#pragma unroll
        for (int c2 = 0; c2 < NB / 2; ++c2) {
            float4 v = src[c2];
            Pn[2 * c2][t]     = make_float2(v.x, v.y);
            Pn[2 * c2 + 1][t] = make_float2(v.z, v.w);
            if (c2 == 0) cur = make_float2(v.x, v.y);
        }
    }
    __syncthreads();
    int lg = t;     // logical position of this thread's row
    int nsw = 0;
#pragma unroll 1
    for (int j = 0; j < NB; ++j) {
        const int par = j & 1;
        // --- packed argmax: [fv bits 31:16 | lg(8) | phys(8)] ---
        unsigned pk = 0u;
        if (act && lg >= j) {
            float fv = fabsf(cur.x) + fabsf(cur.y);
            union { float f; unsigned u; } cu; cu.f = fv;
            pk = (cu.u & 0xFFFF0000u) | ((unsigned)lg << 8) | (unsigned)t;
        }
        unsigned wbest = wave_max_u32_dpp(pk);
        if (lane == 0) rbest4[par][w] = wbest;
        __syncthreads();   // the ONLY barrier per step
        uint4 rb = *(const uint4*)&rbest4[par][0];
        unsigned ga = rb.x >= rb.y ? rb.x : rb.y;
        unsigned gb = rb.z >= rb.w ? rb.z : rb.w;
        unsigned gg = ga >= gb ? ga : gb;
        int w_phys = (int)(gg & 255u);
        int l_w    = (int)((gg >> 8) & 255u);
        float2 d = Pn[j][w_phys];     // broadcast read of pivot diag
        if (t == 0) {
            diag_s[j] = d;
            piv_s[j] = (short)l_w;
            if (l_w != j) nsw++;
        }
        // --- relabel (no data movement) ---
        int oldlg = lg;
        if (t == w_phys) lg = j;
        else if (oldlg == j) lg = l_w;
        float ivn = 1.f / (d.x * d.x + d.y * d.y);
        float inx = d.x * ivn, iny = -d.y * ivn;
        // --- eliminate own row ---
        if (act && lg > j) {
            float2 L = make_float2(cur.x * inx - cur.y * iny,
                                   cur.x * iny + cur.y * inx);
            Pn[j][t] = L;
            if (j < NB - 1) {
                // column j+1 solo -> new cur (feeds next argmax)
                float2 u1 = Pn[j + 1][w_phys];
                float2 v1 = Pn[j + 1][t];
                v1.x -= L.x * u1.x - L.y * u1.y;
                v1.y -= L.x * u1.y + L.y * u1.x;
                Pn[j + 1][t] = v1;
                cur = v1;
                // remaining cols j+2.. in chunks of 8 (pad absorbs overrun)
                int nch = (NB - 2 - j + 7) >> 3;
#pragma unroll 1
                for (int ch = 0; ch < nch; ++ch) {
                    int c0 = j + 2 + ch * 8;
                    const float2* ub = &Pn[c0][w_phys];
                    float2* vb = &Pn[c0][t];
                    float2 uu[8], vv[8];
#pragma unroll
                    for (int cc = 0; cc < 8; ++cc) uu[cc] = ub[(size_t)cc * NE];
#pragma unroll
                    for (int cc = 0; cc < 8; ++cc) vv[cc] = vb[(size_t)cc * NE];
#pragma unroll
                    for (int cc = 0; cc < 8; ++cc) {
                        vv[cc].x -= L.x * uu[cc].x - L.y * uu[cc].y;
                        vv[cc].y -= L.x * uu[cc].y + L.y * uu[cc].x;
                    }
#pragma unroll
                    for (int cc = 0; cc < 8; ++cc) vb[(size_t)cc * NE] = vv[cc];
                }
            }
        }
    }
    if (act && lg < NB) phys_of_s[lg] = (short)t;   // logical->physical map
    // write back own row to its LOGICAL slot (reproduces permuted layout)
    if (act) {
        float4* dst = (float4*)(Am + (size_t)(k0 + lg) * NE + k0);
#pragma unroll
        for (int c2 = 0; c2 < NB / 2; ++c2) {
            float2 e0 = Pn[2 * c2][t], e1 = Pn[2 * c2 + 1][t];
            dst[c2] = make_float4(e0.x, e0.y, e1.x, e1.y);
        }
    }
    __syncthreads();
    // log-det accumulation (wave 0)
    if (w == 0) {
        float lre = 0.f, lim = 0.f;
        if (lane < NB) {
            float2 d = diag_s[lane];
            lre = 0.5f * logf(d.x * d.x + d.y * d.y);
            lim = atan2f(d.y, d.x);
        }
#pragma unroll
        for (int off = 32; off; off >>= 1) {
            lre += __shfl_xor(lre, off, 64);
            lim += __shfl_xor(lim, off, 64);
        }
        if (lane == 0) { acc[2] += lre; acc[3] += lim; }
    }
    if (t == 0) acc[4] += (float)nsw;
    // ---------------- fused trsm ----------------
    if (k0 + NB >= NE) return;
    for (int idx = t; idx < NB * NB; idx += 256) {
        int i2 = idx >> 5, j2 = idx & 31;
        Ls[i2][j2] = Pn[j2][phys_of_s[i2]];
    }
    sigma_s[t] = (short)t;
    if (t < NB) rlist_s[t] = (short)k0;   // dummy default (valid row, never stored)
    __syncthreads();
    if (t == 0) {
        for (int j2 = 0; j2 < NB; ++j2) {
            int p = k0 + (int)piv_s[j2], r1 = k0 + j2;
            short tmp = sigma_s[r1]; sigma_s[r1] = sigma_s[p]; sigma_s[p] = tmp;
        }
        int cnt = 0;
        for (int r2 = k0 + NB; r2 < NE; ++r2)
            if (sigma_s[r2] != r2) rlist_s[cnt++] = (short)r2;
        rcount_s = cnt;
    }
    __syncthreads();
    int ncols = NE - k0 - NB;
    if (t >= ncols) return;
    int col = k0 + NB + t;
    int cnt = rcount_s;
    // gather panel-top rows (post-permutation) — independent loads
    float2 x[NB];
#pragma unroll
    for (int i = 0; i < NB; ++i)
        x[i] = Am[(size_t)sigma_s[k0 + i] * NE + col];
    // gather displaced below-panel rows — independent loads
    float2 extra[NB];
#pragma unroll
    for (int q2 = 0; q2 < NB; ++q2)
        extra[q2] = Am[(size_t)sigma_s[rlist_s[q2]] * NE + col];
    // unit-lower triangular solve, registers + LDS broadcast
#pragma unroll
    for (int i = 1; i < NB; ++i) {
        float2 xi = x[i];
#pragma unroll
        for (int j2 = 0; j2 < i; ++j2) {
            float2 l = Ls[i][j2];
            xi.x -= l.x * x[j2].x - l.y * x[j2].y;
            xi.y -= l.x * x[j2].y + l.y * x[j2].x;
        }
        x[i] = xi;
    }
    // stores (after all loads): U12 rows and permuted below-panel rows
#pragma unroll
    for (int i = 0; i < NB; ++i)
        Am[(size_t)(k0 + i) * NE + col] = x[i];
#pragma unroll
    for (int q2 = 0; q2 < NB; ++q2)
        if (q2 < cnt) Am[(size_t)rlist_s[q2] * NE + col] = extra[q2];
}

// A22 -= L21 @ U12, complex, K=NB. 32x32 tile per block.
__global__ __launch_bounds__(256) void update_k(float2* __restrict__ Am, int k0) {
    __shared__ float2 Lt[NB][NB + 1];
    __shared__ float2 Ut[NB][NB + 1];
    int t = threadIdx.x;
    int r0 = k0 + NB + blockIdx.x * NB;
    int c0 = k0 + NB + blockIdx.y * NB;
    for (int idx = t; idx < NB * NB; idx += 256) {
        int a = idx >> 5, b = idx & 31;
        Lt[a][b] = Am[(size_t)(r0 + a) * NE + k0 + b];
        Ut[a][b] = Am[(size_t)(k0 + a) * NE + c0 + b];
    }
    __syncthreads();
    int lr = t >> 3, lc0 = (t & 7) * 4;
    float2 s0 = {0.f, 0.f}, s1 = {0.f, 0.f}, s2 = {0.f, 0.f}, s3 = {0.f, 0.f};
#pragma unroll
    for (int k = 0; k < NB; ++k) {
        float2 a = Lt[lr][k];
        float2 u0 = Ut[k][lc0 + 0], u1 = Ut[k][lc0 + 1];
        float2 u2 = Ut[k][lc0 + 2], u3 = Ut[k][lc0 + 3];
        s0.x += a.x * u0.x - a.y * u0.y; s0.y += a.x * u0.y + a.y * u0.x;
        s1.x += a.x * u1.x - a.y * u1.y; s1.y += a.x * u1.y + a.y * u1.x;
        s2.x += a.x * u2.x - a.y * u2.y; s2.y += a.x * u2.y + a.y * u2.x;
        s3.x += a.x * u3.x - a.y * u3.y; s3.y += a.x * u3.y + a.y * u3.x;
    }
    size_t base = (size_t)(r0 + lr) * NE + c0 + lc0;
    float2 cc;
    cc = Am[base + 0]; cc.x -= s0.x; cc.y -= s0.y; Am[base + 0] = cc;
    cc = Am[base + 1]; cc.x -= s1.x; cc.y -= s1.y; Am[base + 1] = cc;
    cc = Am[base + 2]; cc.x -= s2.x; cc.y -= s2.y; Am[base + 2] = cc;
    cc = Am[base + 3]; cc.x -= s3.x; cc.y -= s3.y; Am[base + 3] = cc;
}

__global__ void finalize_k(const float* __restrict__ acc, float* __restrict__ out) {
    if (threadIdx.x == 0) {
        float ang = acc[3] + 3.14159265358979323846f * acc[4];
        ang -= 6.283185307179586f * rintf(ang * 0.15915494309189535f);
        out[0] = 0.5f * acc[2] + acc[0];
        out[1] = 0.5f * ang + acc[1];
    }
}

// ---------------- host launch ----------------
extern "C" void kernel_launch(void* const* d_in, const int* in_sizes, int n_in,
                              void* d_out, int out_size, void* d_ws, size_t ws_size,
                              hipStream_t stream) {
    (void)in_sizes; (void)n_in; (void)out_size;
    const float* el   = (const float*)d_in[0];
    const float* Win  = (const float*)d_in[1];
    const float* Wq   = (const float*)d_in[2];
    const float* bq   = (const float*)d_in[3];
    const float* Wk   = (const float*)d_in[4];
    const float* bk   = (const float*)d_in[5];
    const float* Wv   = (const float*)d_in[6];
    const float* bv   = (const float*)d_in[7];
    const float* Wo   = (const float*)d_in[8];
    const float* bo   = (const float*)d_in[9];
    const float* W1   = (const float*)d_in[10];
    const float* ln1s = (const float*)d_in[11];
    const float* ln1b = (const float*)d_in[12];
    const float* W2   = (const float*)d_in[13];
    const float* b2   = (const float*)d_in[14];
    const float* ln2s = (const float*)d_in[15];
    const float* ln2b = (const float*)d_in[16];
    const float* Wor  = (const float*)d_in[17];
    const float* Woi  = (const float*)d_in[18];

    char* wp = (char*)d_ws;
    auto alloc = [&](size_t b) {
        char* r = wp;
        wp += (b + 255) & ~(size_t)255;
        return r;
    };
    int*    ipb  = (int*)alloc((size_t)P_TOT * 4);
    int*    jpb  = (int*)alloc((size_t)P_TOT * 4);
    float2* porb = (float2*)alloc((size_t)P_TOT * 8);
    float2* Am   = (float2*)alloc((size_t)NE * NE * 8);
    float*  acc  = (float*)alloc(256);
    ushort* Wqkv_t = (ushort*)alloc((size_t)2 * 768 * 256 * 2);
    ushort* Woth_t = (ushort*)alloc((size_t)6 * 65536 * 2);
    ushort* Wf_t   = (ushort*)alloc((size_t)2 * 65536 * 2);
    float*  bfuse  = (float*)alloc((size_t)2 * 256 * 4);
    float*  bqkv = (float*)alloc((size_t)2 * 768 * 4);
    size_t fixed = (size_t)(wp - (char*)d_ws);

    // runtime chunk count: prefer 1 (biggest GEMM grids, fewest dispatches)
    int nchunk = 0, PCr = 0, MCr = 0;
    const int cands[3] = {1, 2, 3};
    for (int ci = 0; ci < 3; ++ci) {
        int pc = P_TOT / cands[ci];            // 32640 / 16320 / 10880 (all %64==0)
        size_t mc = (size_t)2 * pc;
        size_t var = 0;
        var += ((mc * 256 * 2 + 255) & ~(size_t)255);   // hb
        var += ((mc * 768 * 2 + 255) & ~(size_t)255);   // qkvb
        if (fixed + var <= ws_size) { nchunk = cands[ci]; PCr = pc; MCr = (int)mc; break; }
    }
    if (!nchunk) {
        zero_k<<<1, 64, 0, stream>>>((float*)d_out);
        return;
    }
    ushort* hb   = (ushort*)alloc((size_t)MCr * 256 * 2);
    ushort* qkvb = (ushort*)alloc((size_t)MCr * 768 * 2);
    int MTr = MCr / 128;

    prep_w_k<<<dim3(8, 8, 12), 256, 0, stream>>>(Wq, Wk, Wv, Wo, W1, W2, Wqkv_t, Woth_t);
    prep_b_k<<<2, 256, 0, stream>>>(bq, bk, bv, bqkv);
    fuse_w_k<<<dim3(8, 8, 2), 256, 0, stream>>>(Wo, W1, Wf_t);
    fuse_b_k<<<2, 256, 0, stream>>>(bo, W1, bfuse);
    idx_k<<<1, 256, 0, stream>>>(ipb, jpb);
    zero_k<<<1, 64, 0, stream>>>(acc);

    for (int c = 0; c < nchunk; ++c) {
        int P0 = c * PCr;
        embed_k<<<MCr / 4, 256, 0, stream>>>(el, Win, ipb, jpb, hb, P0);
        for (int l = 0; l < NL; ++l) {
            gemm_k<true, false><<<MTr * 6, 256, 0, stream>>>(
                hb, 256, Wqkv_t + (size_t)l * 768 * 256, bqkv + l * 768, nullptr, 0, qkvb, 768, 6);
            attn_k<<<PCr, 256, 0, stream>>>(qkvb);
            // hb = LN( o@Wf + bfuse + hb )
            gemm_ln_k<false><<<MTr, 256, 0, stream>>>(
                qkvb, 768, Wf_t + (size_t)l * 65536, bfuse + l * 256, hb,
                ln1s + l * 256, ln1b + l * 256, hb);
            // hb = LN( hb + tanh(hb@W2 + b2) )
            gemm_ln_k<true><<<MTr, 256, 0, stream>>>(
                hb, 256, Woth_t + (size_t)(l * 3 + 2) * 65536, b2 + l * 256, hb,
                ln2s + l * 256, ln2b + l * 256, hb);
        }
        orb_k<<<PCr / 4, 256, 0, stream>>>(hb, Wor, Woi, el, ipb, jpb, porb, P0);
    }
    assemble_k<<<NE, 256, 0, stream>>>(el, porb, Am, acc);

    for (int p = 0; p < NPANEL; ++p) {
        int k0 = p * NB;
        panel_k<<<1, 256, 0, stream>>>(Am, acc, k0);   // panel + fused trsm
        int m = NE - k0 - NB;
        if (m > 0) {
            dim3 ug(m / NB, m / NB);
            update_k<<<ug, 256, 0, stream>>>(Am, k0);
        }
    }
    finalize_k<<<1, 64, 0, stream>>>(acc, (float*)d_out);
}

// Round 9
// 940.761 us; speedup vs baseline: 1.0657x; 1.0657x over previous
//
// R13: R12 with gemm_ln_k re-geometried to 512 threads / 8 waves (2 row x 4 col
//      wave grid): per-thread acc back to [4][4] (64 VGPR accumulator, gemm_k's
//      proven budget), epilogue halved, LN reduce = shfl(16) + 4-partial LDS
//      combine. Fixes R12's measured VGPR-204/occupancy-10% cliff.
//      Fusion B (trsm inside panel_k) and everything else kept from R12.
#include <hip/hip_runtime.h>
#include <math.h>
#include <stdint.h>

#define NE 256
#define DD 256
#define NL 2
#define P_TOT 32640          // NE*(NE-1)/2
#define NB 32                // LU panel width
#define NBP 40               // padded panel columns (chunk overrun, never read)
#define NPANEL (NE / NB)
#define NXCD 8

typedef __bf16 bf16x8 __attribute__((ext_vector_type(8)));
typedef float f32x4 __attribute__((ext_vector_type(4)));

__device__ __forceinline__ float bf2f(ushort h) {
    union { unsigned u; float f; } c; c.u = ((unsigned)h) << 16; return c.f;
}
__device__ __forceinline__ ushort f2bf(float f) {
    union { float f; unsigned u; } c; c.f = f;
    unsigned u = c.u;
    return (ushort)((u + 0x7fffu + ((u >> 16) & 1u)) >> 16);
}

#define GLD16(gp, lp) __builtin_amdgcn_global_load_lds( \
    (const __attribute__((address_space(1))) unsigned int*)(uintptr_t)(gp), \
    (__attribute__((address_space(3))) unsigned int*)(uintptr_t)(lp), 16, 0, 0)

// ---------------- small helpers ----------------
__global__ void idx_k(int* __restrict__ ip, int* __restrict__ jp) {
    int i = threadIdx.x;  // 0..255
    int base = i * 255 - (i * (i - 1)) / 2;
    for (int j = i + 1; j < NE; ++j) {
        ip[base + j - i - 1] = i;
        jp[base + j - i - 1] = j;
    }
}

__global__ void zero_k(float* __restrict__ acc) {
    if (threadIdx.x < 8) acc[threadIdx.x] = 0.f;
}

// ---------------- weight prep: Bt[n][k] = W[k][n] in bf16 ----------------
__global__ __launch_bounds__(256) void prep_w_k(
    const float* __restrict__ Wq, const float* __restrict__ Wk, const float* __restrict__ Wv,
    const float* __restrict__ Wo, const float* __restrict__ W1, const float* __restrict__ W2,
    ushort* __restrict__ Wqkv_t, ushort* __restrict__ Woth_t) {
    __shared__ float Ts[32][33];
    int z = blockIdx.z, l = z / 6, m = z % 6;
    const float* src;
    ushort* dst;
    if (m == 0)      { src = Wq + l * 65536; dst = Wqkv_t + (size_t)l * 768 * 256 + 0 * 65536; }
    else if (m == 1) { src = Wk + l * 65536; dst = Wqkv_t + (size_t)l * 768 * 256 + 1 * 65536; }
    else if (m == 2) { src = Wv + l * 65536; dst = Wqkv_t + (size_t)l * 768 * 256 + 2 * 65536; }
    else             { src = (m == 3 ? Wo : m == 4 ? W1 : W2) + l * 65536;
                       dst = Woth_t + (size_t)(l * 3 + (m - 3)) * 65536; }
    int k0 = blockIdx.x * 32, n0 = blockIdx.y * 32;
    int t = threadIdx.x, tr = t >> 5, tc = t & 31;
    for (int i = tr; i < 32; i += 8) Ts[i][tc] = src[(size_t)(k0 + i) * 256 + n0 + tc];
    __syncthreads();
    for (int i = tr; i < 32; i += 8) dst[(size_t)(n0 + i) * 256 + k0 + tc] = f2bf(Ts[tc][i]);
}

__global__ void prep_b_k(const float* __restrict__ bq, const float* __restrict__ bk,
                         const float* __restrict__ bv, float* __restrict__ bqkv) {
    int l = blockIdx.x, t = threadIdx.x;
    bqkv[l * 768 + t] = bq[l * 256 + t];
    bqkv[l * 768 + 256 + t] = bk[l * 256 + t];
    bqkv[l * 768 + 512 + t] = bv[l * 256 + t];
}

// ---------------- fused weight: Wf_t[l][n][d] = bf16( sum_m Wo[l][d][m]*W1[l][m][n] )
__global__ __launch_bounds__(256) void fuse_w_k(
    const float* __restrict__ Wo, const float* __restrict__ W1,
    ushort* __restrict__ Wf_t) {
    __shared__ float WoS[32][33];   // WoS[d][m]
    __shared__ float W1S[32][33];   // W1S[m][n]
    int l = blockIdx.z;
    int n0 = blockIdx.x * 32, d0 = blockIdx.y * 32;
    const float* wo = Wo + l * 65536;
    const float* w1 = W1 + l * 65536;
    int t = threadIdx.x, ty = t >> 5, tx = t & 31;
    float acc4[4] = {0.f, 0.f, 0.f, 0.f};
    for (int m0 = 0; m0 < 256; m0 += 32) {
        __syncthreads();
        for (int i = ty; i < 32; i += 8) {
            WoS[i][tx] = wo[(size_t)(d0 + i) * 256 + m0 + tx];
            W1S[i][tx] = w1[(size_t)(m0 + i) * 256 + n0 + tx];
        }
        __syncthreads();
#pragma unroll
        for (int jm = 0; jm < 32; ++jm) {
            float a = WoS[tx][jm];
#pragma unroll
            for (int q = 0; q < 4; ++q)
                acc4[q] += a * W1S[jm][ty + 8 * q];
        }
    }
#pragma unroll
    for (int q = 0; q < 4; ++q)
        Wf_t[(size_t)l * 65536 + (size_t)(n0 + ty + 8 * q) * 256 + d0 + tx] = f2bf(acc4[q]);
}

// bfuse[l][n] = sum_m bo[l][m]*W1[l][m][n]
__global__ void fuse_b_k(const float* __restrict__ bo, const float* __restrict__ W1,
                         float* __restrict__ bfuse) {
    int l = blockIdx.x, n = threadIdx.x;
    const float* w1 = W1 + l * 65536;
    const float* b = bo + l * 256;
    float s = 0.f;
    for (int m = 0; m < 256; ++m) s += b[m] * w1[(size_t)m * 256 + n];
    bfuse[l * 256 + n] = s;
}

// ---------------- embedding: h = feat @ W_in (bf16 out) ----------------
__global__ __launch_bounds__(256) void embed_k(
    const float* __restrict__ el, const float* __restrict__ Win,
    const int* __restrict__ ip, const int* __restrict__ jp,
    ushort* __restrict__ h, int P0) {
    int w = threadIdx.x >> 6, lane = threadIdx.x & 63;
    int r = blockIdx.x * 4 + w;
    int gp = P0 + (r >> 1);
    int e = (r & 1) ? jp[gp] : ip[gp];
    float th = el[2 * e], ph = el[2 * e + 1];
    float st = sinf(th);
    float f0 = cosf(th), f1 = st * cosf(ph), f2 = st * sinf(ph);
    int n = lane * 4;
    float4 w0 = *(const float4*)&Win[n];
    float4 w1 = *(const float4*)&Win[256 + n];
    float4 w2 = *(const float4*)&Win[512 + n];
    ushort4 o;
    o.x = f2bf(f0 * w0.x + f1 * w1.x + f2 * w2.x);
    o.y = f2bf(f0 * w0.y + f1 * w1.y + f2 * w2.y);
    o.z = f2bf(f0 * w0.z + f1 * w1.z + f2 * w2.z);
    o.w = f2bf(f0 * w0.w + f1 * w1.w + f2 * w2.w);
    *(ushort4*)&h[(size_t)r * 256 + n] = o;
}

// ---------------- bf16 MFMA GEMM: C = A@B (+bias) (+residual) ----------------
// 1D grid, XCD-chunked bijective swizzle (see R10).
template <bool BIAS, bool RES>
__global__ __launch_bounds__(256) void gemm_k(
    const ushort* __restrict__ A, int lda,
    const ushort* __restrict__ Bt,
    const float* __restrict__ bias,
    const ushort* __restrict__ Rm, int ldr,
    ushort* __restrict__ C, int ldc, int ny) {
    __shared__ ushort As[128 * 64];
    __shared__ ushort Bs[128 * 64];
    int t = threadIdx.x, lane = t & 63, w = t >> 6;
    int nwg = gridDim.x;
    int orig = blockIdx.x;
    int qq = nwg / NXCD, rr = nwg % NXCD;
    int xcd = orig % NXCD, idx = orig / NXCD;
    int wg = (xcd < rr ? xcd * (qq + 1) : rr * (qq + 1) + (xcd - rr) * qq) + idx;
    int row0 = (wg / ny) * 128, col0 = (wg % ny) * 128;
    int lrow = lane >> 3;                 // row within 8-row staging chunk
    int kx = ((lane & 7) ^ lrow) << 3;    // swizzled k element offset
    const ushort* gA = A + (size_t)(row0 + w * 32 + lrow) * lda + kx;
    const ushort* gB = Bt + (size_t)(col0 + w * 32 + lrow) * 256 + kx;
    f32x4 acc[4][4];
#pragma unroll
    for (int i = 0; i < 4; ++i)
#pragma unroll
        for (int j = 0; j < 4; ++j) acc[i][j] = (f32x4){0.f, 0.f, 0.f, 0.f};
    int wm = w >> 1, wn = w & 1;
    int mbase = wm * 64 + (lane & 15);
    int nbase = wn * 64 + (lane & 15);
    int l7 = lane & 7;
    for (int k0 = 0; k0 < 256; k0 += 64) {
        __syncthreads();
#pragma unroll
        for (int c2 = 0; c2 < 4; ++c2) {
            GLD16(gA + (size_t)(c2 * 8) * lda + k0, &As[(w * 4 + c2) * 512]);
            GLD16(gB + (size_t)(c2 * 8) * 256 + k0, &Bs[(w * 4 + c2) * 512]);
        }
        __syncthreads();
#pragma unroll
        for (int ks = 0; ks < 2; ++ks) {
            int kb = ks * 4 + (lane >> 4);
            bf16x8 af[4], bfr[4];
#pragma unroll
            for (int tm = 0; tm < 4; ++tm)
                af[tm] = *(const bf16x8*)&As[(mbase + tm * 16) * 64 + ((kb ^ l7) << 3)];
#pragma unroll
            for (int tn = 0; tn < 4; ++tn)
                bfr[tn] = *(const bf16x8*)&Bs[(nbase + tn * 16) * 64 + ((kb ^ l7) << 3)];
#pragma unroll
            for (int tm = 0; tm < 4; ++tm)
#pragma unroll
                for (int tn = 0; tn < 4; ++tn)
                    acc[tm][tn] = __builtin_amdgcn_mfma_f32_16x16x32_bf16(
                        af[tm], bfr[tn], acc[tm][tn], 0, 0, 0);
        }
    }
    int q = lane >> 4;
    int crow = row0 + wm * 64 + q * 4;
    int ccol = col0 + wn * 64 + (lane & 15);
#pragma unroll
    for (int tm = 0; tm < 4; ++tm)
#pragma unroll
        for (int r = 0; r < 4; ++r) {
            int row = crow + tm * 16 + r;
#pragma unroll
            for (int tn = 0; tn < 4; ++tn) {
                int col = ccol + tn * 16;
                float v = acc[tm][tn][r];
                if (BIAS) v += bias[col];
                if (RES) v += bf2f(Rm[(size_t)row * ldr + col]);
                C[(size_t)row * ldc + col] = f2bf(v);
            }
        }
}

// ---------------- GEMM (128x256 full-row tile, 512 thr) + LayerNorm epilogue --
// 8 waves: wm = w>>2 (2 row groups x 64), wn = w&3 (4 col groups x 64).
// Per-thread acc[4][4] (gemm_k's proven 64-VGPR budget). LN per-row stats:
// shfl over 16-lane col group + 4-partial LDS combine. Block owns complete
// rows -> in-place hb update race-free.
template <bool TANH>
__global__ __launch_bounds__(512) void gemm_ln_k(
    const ushort* __restrict__ A, int lda,
    const ushort* __restrict__ Bt,
    const float* __restrict__ bias,
    const ushort* __restrict__ Rm,            // residual, ld 256
    const float* __restrict__ sc, const float* __restrict__ bi,
    ushort* __restrict__ C) {                 // ld 256
    __shared__ ushort As[128 * 64];           // 16 KB
    __shared__ ushort Bs[256 * 64];           // 32 KB
    __shared__ float red_s[128][4][2];        // 4 KB [row][wn][{sum,sumsq}]
    int t = threadIdx.x, lane = t & 63, w = t >> 6;
    int row0 = blockIdx.x * 128;
    int lrow = lane >> 3;
    int kx = ((lane & 7) ^ lrow) << 3;
    const ushort* gA = A + (size_t)(row0 + w * 16 + lrow) * lda + kx;
    const ushort* gB = Bt + (size_t)(w * 32 + lrow) * 256 + kx;
    f32x4 acc[4][4];
#pragma unroll
    for (int i = 0; i < 4; ++i)
#pragma unroll
        for (int j = 0; j < 4; ++j) acc[i][j] = (f32x4){0.f, 0.f, 0.f, 0.f};
    int wm = w >> 2, wn = w & 3;
    int mbase = wm * 64 + (lane & 15);
    int nbase = wn * 64 + (lane & 15);
    int l7 = lane & 7;
    for (int k0 = 0; k0 < 256; k0 += 64) {
        __syncthreads();
#pragma unroll
        for (int c2 = 0; c2 < 2; ++c2)
            GLD16(gA + (size_t)(c2 * 8) * lda + k0, &As[(w * 2 + c2) * 512]);
#pragma unroll
        for (int c2 = 0; c2 < 4; ++c2)
            GLD16(gB + (size_t)(c2 * 8) * 256 + k0, &Bs[(w * 4 + c2) * 512]);
        __syncthreads();
#pragma unroll
        for (int ks = 0; ks < 2; ++ks) {
            int kb = ks * 4 + (lane >> 4);
            bf16x8 af[4], bfr[4];
#pragma unroll
            for (int tm = 0; tm < 4; ++tm)
                af[tm] = *(const bf16x8*)&As[(mbase + tm * 16) * 64 + ((kb ^ l7) << 3)];
#pragma unroll
            for (int tn = 0; tn < 4; ++tn)
                bfr[tn] = *(const bf16x8*)&Bs[(nbase + tn * 16) * 64 + ((kb ^ l7) << 3)];
#pragma unroll
            for (int tm = 0; tm < 4; ++tm)
#pragma unroll
                for (int tn = 0; tn < 4; ++tn)
                    acc[tm][tn] = __builtin_amdgcn_mfma_f32_16x16x32_bf16(
                        af[tm], bfr[tn], acc[tm][tn], 0, 0, 0);
        }
    }
    int q = lane >> 4;
    float bias4[4];
#pragma unroll
    for (int tn = 0; tn < 4; ++tn) bias4[tn] = bias[wn * 64 + (lane & 15) + tn * 16];
    // pass 1: x = bias/res/tanh applied (stored back into acc), row partials
#pragma unroll
    for (int tm = 0; tm < 4; ++tm)
#pragma unroll
        for (int r = 0; r < 4; ++r) {
            int rl = wm * 64 + tm * 16 + q * 4 + r;
            int row = row0 + rl;
            float s = 0.f, sq = 0.f;
#pragma unroll
            for (int tn = 0; tn < 4; ++tn) {
                int col = wn * 64 + (lane & 15) + tn * 16;
                float v = acc[tm][tn][r] + bias4[tn];
                float x;
                if (TANH) x = bf2f(Rm[(size_t)row * 256 + col]) + tanhf(v);
                else      x = v + bf2f(Rm[(size_t)row * 256 + col]);
                acc[tm][tn][r] = x;
                s += x; sq += x * x;
            }
#pragma unroll
            for (int off = 1; off <= 8; off <<= 1) {
                s += __shfl_xor(s, off, 64);
                sq += __shfl_xor(sq, off, 64);
            }
            if ((lane & 15) == 0) { red_s[rl][wn][0] = s; red_s[rl][wn][1] = sq; }
        }
    __syncthreads();
    // pass 2: normalize + affine + store
    float sc4[4], bi4[4];
#pragma unroll
    for (int tn = 0; tn < 4; ++tn) {
        int col = wn * 64 + (lane & 15) + tn * 16;
        sc4[tn] = sc[col]; bi4[tn] = bi[col];
    }
#pragma unroll
    for (int tm = 0; tm < 4; ++tm)
#pragma unroll
        for (int r = 0; r < 4; ++r) {
            int rl = wm * 64 + tm * 16 + q * 4 + r;
            int row = row0 + rl;
            float m = (red_s[rl][0][0] + red_s[rl][1][0] +
                       red_s[rl][2][0] + red_s[rl][3][0]) * (1.f / 256.f);
            float var = (red_s[rl][0][1] + red_s[rl][1][1] +
                         red_s[rl][2][1] + red_s[rl][3][1]) * (1.f / 256.f) - m * m;
            float rs = rsqrtf(var + 1e-5f);
#pragma unroll
            for (int tn = 0; tn < 4; ++tn) {
                int col = wn * 64 + (lane & 15) + tn * 16;
                C[(size_t)row * 256 + col] =
                    f2bf((acc[tm][tn][r] - m) * rs * sc4[tn] + bi4[tn]);
            }
        }
}

// ---------------- attention (seq=2) on fused qkv [row,768] ----------------
__global__ __launch_bounds__(256) void attn_k(ushort* __restrict__ qkv) {
    int wid = threadIdx.x >> 6, lane = threadIdx.x & 63;
    int gw = blockIdx.x * 4 + wid;
    int p = gw >> 2, hh = gw & 3;
    size_t r0 = (size_t)(2 * p) * 768 + hh * 64 + lane;
    size_t r1 = r0 + 768;
    float q0 = bf2f(qkv[r0]) * 0.125f, q1 = bf2f(qkv[r1]) * 0.125f;
    float k0 = bf2f(qkv[r0 + 256]), k1 = bf2f(qkv[r1 + 256]);
    float v0 = bf2f(qkv[r0 + 512]), v1 = bf2f(qkv[r1 + 512]);
    float s00 = q0 * k0, s01 = q0 * k1, s10 = q1 * k0, s11 = q1 * k1;
#pragma unroll
    for (int off = 32; off; off >>= 1) {
        s00 += __shfl_xor(s00, off, 64);
        s01 += __shfl_xor(s01, off, 64);
        s10 += __shfl_xor(s10, off, 64);
        s11 += __shfl_xor(s11, off, 64);
    }
    float m0 = fmaxf(s00, s01), m1 = fmaxf(s10, s11);
    float e00 = expf(s00 - m0), e01 = expf(s01 - m0);
    float e10 = expf(s10 - m1), e11 = expf(s11 - m1);
    float i0 = 1.f / (e00 + e01), i1 = 1.f / (e10 + e11);
    float o0 = (e00 * i0) * v0 + (e01 * i0) * v1;
    float o1 = (e10 * i1) * v0 + (e11 * i1) * v1;
    qkv[r0] = f2bf(o0);
    qkv[r1] = f2bf(o1);
}

// ---------------- per-pair orbitals + 2x2 det ----------------
__global__ __launch_bounds__(256) void orb_k(
    const ushort* __restrict__ h, const float* __restrict__ Wr, const float* __restrict__ Wi,
    const float* __restrict__ el, const int* __restrict__ ip, const int* __restrict__ jp,
    float2* __restrict__ porb, int P0) {
    int w = threadIdx.x >> 6, lane = threadIdx.x & 63;
    int p = blockIdx.x * 4 + w;
    const ushort* h0 = h + (size_t)(2 * p) * 256;
    int d0 = lane * 4;
    ushort4 a0 = *(const ushort4*)&h0[d0];
    ushort4 a1 = *(const ushort4*)&h0[256 + d0];
    float x0[4] = {bf2f(a0.x), bf2f(a0.y), bf2f(a0.z), bf2f(a0.w)};
    float x1[4] = {bf2f(a1.x), bf2f(a1.y), bf2f(a1.z), bf2f(a1.w)};
    float wrv[8], wiv[8];
    *(float4*)&wrv[0] = *(const float4*)&Wr[2 * d0];
    *(float4*)&wrv[4] = *(const float4*)&Wr[2 * d0 + 4];
    *(float4*)&wiv[0] = *(const float4*)&Wi[2 * d0];
    *(float4*)&wiv[4] = *(const float4*)&Wi[2 * d0 + 4];
    float s[8] = {0, 0, 0, 0, 0, 0, 0, 0};
#pragma unroll
    for (int u = 0; u < 4; ++u) {
        s[0] += x0[u] * wrv[2 * u];     s[1] += x0[u] * wiv[2 * u];
        s[2] += x0[u] * wrv[2 * u + 1]; s[3] += x0[u] * wiv[2 * u + 1];
        s[4] += x1[u] * wrv[2 * u];     s[5] += x1[u] * wiv[2 * u];
        s[6] += x1[u] * wrv[2 * u + 1]; s[7] += x1[u] * wiv[2 * u + 1];
    }
#pragma unroll
    for (int off = 32; off; off >>= 1) {
#pragma unroll
        for (int q2 = 0; q2 < 8; ++q2) s[q2] += __shfl_xor(s[q2], off, 64);
    }
    if (lane == 0) {
        int gp = P0 + p;
        int i = ip[gp], j = jp[gp];
        float thi = el[2 * i], phi_ = el[2 * i + 1];
        float thj = el[2 * j], phj = el[2 * j + 1];
        float chi = cosf(thi * 0.5f), shi = sinf(thi * 0.5f);
        float chj = cosf(thj * 0.5f), shj = sinf(thj * 0.5f);
        float cpi = cosf(phi_ * 0.5f), spi = sinf(phi_ * 0.5f);
        float cpj = cosf(phj * 0.5f), spj = sinf(phj * 0.5f);
        float uix = chi * cpi, uiy = chi * spi;
        float vix = shi * cpi, viy = -shi * spi;
        float ujx = chj * cpj, ujy = chj * spj;
        float vjx = shj * cpj, vjy = -shj * spj;
        float crx = (uix * vjx - uiy * vjy) - (ujx * vix - ujy * viy);
        float cry = (uix * vjy + uiy * vjx) - (ujx * viy + ujy * vix);
        float chord2 = crx * crx + cry * cry;
        float trunc = 1.f - expf(-100.f * chord2);
        float t2 = trunc * trunc;
        float dr = (s[0] * s[6] - s[1] * s[7]) - (s[2] * s[4] - s[3] * s[5]);
        float di = (s[0] * s[7] + s[1] * s[6]) - (s[2] * s[5] + s[3] * s[4]);
        porb[gp] = make_float2(dr * t2, di * t2);
    }
}

// ---------------- assemble A = pf + cusp, accumulate log_bos ----------------
__global__ __launch_bounds__(256) void assemble_k(
    const float* __restrict__ el, const float2* __restrict__ porb,
    float2* __restrict__ Am, float* acc) {
    __shared__ float sre[256], sim[256];
    int idx = blockIdx.x * 256 + threadIdx.x;
    int i = idx >> 8, j = idx & 255;
    float thi = el[2 * i], phi_ = el[2 * i + 1];
    float thj = el[2 * j], phj = el[2 * j + 1];
    float chi = cosf(thi * 0.5f), shi = sinf(thi * 0.5f);
    float chj = cosf(thj * 0.5f), shj = sinf(thj * 0.5f);
    float cpi = cosf(phi_ * 0.5f), spi = sinf(phi_ * 0.5f);
    float cpj = cosf(phj * 0.5f), spj = sinf(phj * 0.5f);
    float uix = chi * cpi, uiy = chi * spi;
    float vix = shi * cpi, viy = -shi * spi;
    float ujx = chj * cpj, ujy = chj * spj;
    float vjx = shj * cpj, vjy = -shj * spj;
    float ex = (uix * vjx - uiy * vjy) - (ujx * vix - ujy * viy);
    float ey = (uix * vjy + uiy * vjx) - (ujx * viy + ujy * vix);
    float pfx = 0.f, pfy = 0.f;
    if (i < j) {
        int pp = i * 255 - (i * (i - 1)) / 2 + (j - i - 1);
        float2 t = porb[pp]; pfx = t.x; pfy = t.y;
    } else if (i > j) {
        int pp = j * 255 - (j * (j - 1)) / 2 + (i - j - 1);
        float2 t = porb[pp]; pfx = -t.x; pfy = -t.y;
    }
    float eye = (i == j) ? 1.f : 0.f;
    float ecx = ex + eye, ecy = ey;
    float wgt = expf(-100.f * (ecx * ecx + ecy * ecy));
    Am[idx] = make_float2(pfx + ecx * wgt, pfy + ecy * wgt);
    float lre = 0.f, lim = 0.f;
    if (i != j) {
        float r2 = ex * ex + ey * ey;
        lre = 0.5f * logf(0.01f + r2);
        lim = atan2f(ey, ex);
    }
    sre[threadIdx.x] = lre; sim[threadIdx.x] = lim;
    __syncthreads();
    for (int s2 = 128; s2; s2 >>= 1) {
        if (threadIdx.x < s2) {
            sre[threadIdx.x] += sre[threadIdx.x + s2];
            sim[threadIdx.x] += sim[threadIdx.x + s2];
        }
        __syncthreads();
    }
    if (threadIdx.x == 0) {
        atomicAdd(acc + 0, sre[0]);
        atomicAdd(acc + 1, sim[0]);
    }
}

// ---------------- LU panel v8 + fused trsm ----------------
__device__ __forceinline__ unsigned wave_max_u32_dpp(unsigned m) {
#define DPP_STEP(ctrl) { \
    unsigned tmp_ = (unsigned)__builtin_amdgcn_update_dpp((int)m, (int)m, ctrl, 0xf, 0xf, false); \
    m = (m >= tmp_) ? m : tmp_; }
    DPP_STEP(0x111)  // row_shr:1
    DPP_STEP(0x112)  // row_shr:2
    DPP_STEP(0x114)  // row_shr:4
    DPP_STEP(0x118)  // row_shr:8
    DPP_STEP(0x142)  // row_bcast:15
    DPP_STEP(0x143)  // row_bcast:31
#undef DPP_STEP
    return (unsigned)__builtin_amdgcn_readlane((int)m, 63);
}

__global__ __launch_bounds__(256) void panel_k(
    float2* __restrict__ Am, float* __restrict__ acc, int k0) {
    __shared__ float2 Pn[NBP][NE];                // 80 KB padded transposed panel
    __shared__ alignas(16) unsigned rbest4[2][4]; // parity double-buffered
    __shared__ float2 diag_s[NB];
    __shared__ short piv_s[NB];
    __shared__ short phys_of_s[NB];
    __shared__ float2 Ls[NB][NB + 1];             // fused-trsm L11 stage
    __shared__ short sigma_s[NE];
    __shared__ short rlist_s[NB];
    __shared__ int rcount_s;
    int t = threadIdx.x, lane = t & 63, w = t >> 6;
    int nr = NE - k0;
    bool act = t < nr;
    float2 cur = make_float2(0.f, 0.f);   // own value at current pivot column
    if (act) {
        const float4* src = (const float4*)(Am + (size_t)(k0 + t) * NE + k0);
#pragma unroll
        for (int c2 = 0; c2 < NB / 2; ++c2) {
            float4 v = src[c2];
            Pn[2 * c2][t]     = make_float2(v.x, v.y);
            Pn[2 * c2 + 1][t] = make_float2(v.z, v.w);
            if (c2 == 0) cur = make_float2(v.x, v.y);
        }
    }
    __syncthreads();
    int lg = t;     // logical position of this thread's row
    int nsw = 0;
#pragma unroll 1
    for (int j = 0; j < NB; ++j) {
        const int par = j & 1;
        // --- packed argmax: [fv bits 31:16 | lg(8) | phys(8)] ---
        unsigned pk = 0u;
        if (act && lg >= j) {
            float fv = fabsf(cur.x) + fabsf(cur.y);
            union { float f; unsigned u; } cu; cu.f = fv;
            pk = (cu.u & 0xFFFF0000u) | ((unsigned)lg << 8) | (unsigned)t;
        }
        unsigned wbest = wave_max_u32_dpp(pk);
        if (lane == 0) rbest4[par][w] = wbest;
        __syncthreads();   // the ONLY barrier per step
        uint4 rb = *(const uint4*)&rbest4[par][0];
        unsigned ga = rb.x >= rb.y ? rb.x : rb.y;
        unsigned gb = rb.z >= rb.w ? rb.z : rb.w;
        unsigned gg = ga >= gb ? ga : gb;
        int w_phys = (int)(gg & 255u);
        int l_w    = (int)((gg >> 8) & 255u);
        float2 d = Pn[j][w_phys];     // broadcast read of pivot diag
        if (t == 0) {
            diag_s[j] = d;
            piv_s[j] = (short)l_w;
            if (l_w != j) nsw++;
        }
        // --- relabel (no data movement) ---
        int oldlg = lg;
        if (t == w_phys) lg = j;
        else if (oldlg == j) lg = l_w;
        float ivn = 1.f / (d.x * d.x + d.y * d.y);
        float inx = d.x * ivn, iny = -d.y * ivn;
        // --- eliminate own row ---
        if (act && lg > j) {
            float2 L = make_float2(cur.x * inx - cur.y * iny,
                                   cur.x * iny + cur.y * inx);
            Pn[j][t] = L;
            if (j < NB - 1) {
                // column j+1 solo -> new cur (feeds next argmax)
                float2 u1 = Pn[j + 1][w_phys];
                float2 v1 = Pn[j + 1][t];
                v1.x -= L.x * u1.x - L.y * u1.y;
                v1.y -= L.x * u1.y + L.y * u1.x;
                Pn[j + 1][t] = v1;
                cur = v1;
                // remaining cols j+2.. in chunks of 8 (pad absorbs overrun)
                int nch = (NB - 2 - j + 7) >> 3;
#pragma unroll 1
                for (int ch = 0; ch < nch; ++ch) {
                    int c0 = j + 2 + ch * 8;
                    const float2* ub = &Pn[c0][w_phys];
                    float2* vb = &Pn[c0][t];
                    float2 uu[8], vv[8];
#pragma unroll
                    for (int cc = 0; cc < 8; ++cc) uu[cc] = ub[(size_t)cc * NE];
#pragma unroll
                    for (int cc = 0; cc < 8; ++cc) vv[cc] = vb[(size_t)cc * NE];
#pragma unroll
                    for (int cc = 0; cc < 8; ++cc) {
                        vv[cc].x -= L.x * uu[cc].x - L.y * uu[cc].y;
                        vv[cc].y -= L.x * uu[cc].y + L.y * uu[cc].x;
                    }
#pragma unroll
                    for (int cc = 0; cc < 8; ++cc) vb[(size_t)cc * NE] = vv[cc];
                }
            }
        }
    }
    if (act && lg < NB) phys_of_s[lg] = (short)t;   // logical->physical map
    // write back own row to its LOGICAL slot (reproduces permuted layout)
    if (act) {
        float4* dst = (float4*)(Am + (size_t)(k0 + lg) * NE + k0);
#pragma unroll
        for (int c2 = 0; c2 < NB / 2; ++c2) {
            float2 e0 = Pn[2 * c2][t], e1 = Pn[2 * c2 + 1][t];
            dst[c2] = make_float4(e0.x, e0.y, e1.x, e1.y);
        }
    }
    __syncthreads();
    // log-det accumulation (wave 0)
    if (w == 0) {
        float lre = 0.f, lim = 0.f;
        if (lane < NB) {
            float2 d = diag_s[lane];
            lre = 0.5f * logf(d.x * d.x + d.y * d.y);
            lim = atan2f(d.y, d.x);
        }
#pragma unroll
        for (int off = 32; off; off >>= 1) {
            lre += __shfl_xor(lre, off, 64);
            lim += __shfl_xor(lim, off, 64);
        }
        if (lane == 0) { acc[2] += lre; acc[3] += lim; }
    }
    if (t == 0) acc[4] += (float)nsw;
    // ---------------- fused trsm ----------------
    if (k0 + NB >= NE) return;
    for (int idx = t; idx < NB * NB; idx += 256) {
        int i2 = idx >> 5, j2 = idx & 31;
        Ls[i2][j2] = Pn[j2][phys_of_s[i2]];
    }
    sigma_s[t] = (short)t;
    if (t < NB) rlist_s[t] = (short)k0;   // dummy default (valid row, never stored)
    __syncthreads();
    if (t == 0) {
        for (int j2 = 0; j2 < NB; ++j2) {
            int p = k0 + (int)piv_s[j2], r1 = k0 + j2;
            short tmp = sigma_s[r1]; sigma_s[r1] = sigma_s[p]; sigma_s[p] = tmp;
        }
        int cnt = 0;
        for (int r2 = k0 + NB; r2 < NE; ++r2)
            if (sigma_s[r2] != r2) rlist_s[cnt++] = (short)r2;
        rcount_s = cnt;
    }
    __syncthreads();
    int ncols = NE - k0 - NB;
    if (t >= ncols) return;
    int col = k0 + NB + t;
    int cnt = rcount_s;
    // gather panel-top rows (post-permutation) — independent loads
    float2 x[NB];
#pragma unroll
    for (int i = 0; i < NB; ++i)
        x[i] = Am[(size_t)sigma_s[k0 + i] * NE + col];
    // gather displaced below-panel rows — independent loads
    float2 extra[NB];
#pragma unroll
    for (int q2 = 0; q2 < NB; ++q2)
        extra[q2] = Am[(size_t)sigma_s[rlist_s[q2]] * NE + col];
    // unit-lower triangular solve, registers + LDS broadcast
#pragma unroll
    for (int i = 1; i < NB; ++i) {
        float2 xi = x[i];
#pragma unroll
        for (int j2 = 0; j2 < i; ++j2) {
            float2 l = Ls[i][j2];
            xi.x -= l.x * x[j2].x - l.y * x[j2].y;
            xi.y -= l.x * x[j2].y + l.y * x[j2].x;
        }
        x[i] = xi;
    }
    // stores (after all loads): U12 rows and permuted below-panel rows
#pragma unroll
    for (int i = 0; i < NB; ++i)
        Am[(size_t)(k0 + i) * NE + col] = x[i];
#pragma unroll
    for (int q2 = 0; q2 < NB; ++q2)
        if (q2 < cnt) Am[(size_t)rlist_s[q2] * NE + col] = extra[q2];
}

// A22 -= L21 @ U12, complex, K=NB. 32x32 tile per block.
__global__ __launch_bounds__(256) void update_k(float2* __restrict__ Am, int k0) {
    __shared__ float2 Lt[NB][NB + 1];
    __shared__ float2 Ut[NB][NB + 1];
    int t = threadIdx.x;
    int r0 = k0 + NB + blockIdx.x * NB;
    int c0 = k0 + NB + blockIdx.y * NB;
    for (int idx = t; idx < NB * NB; idx += 256) {
        int a = idx >> 5, b = idx & 31;
        Lt[a][b] = Am[(size_t)(r0 + a) * NE + k0 + b];
        Ut[a][b] = Am[(size_t)(k0 + a) * NE + c0 + b];
    }
    __syncthreads();
    int lr = t >> 3, lc0 = (t & 7) * 4;
    float2 s0 = {0.f, 0.f}, s1 = {0.f, 0.f}, s2 = {0.f, 0.f}, s3 = {0.f, 0.f};
#pragma unroll
    for (int k = 0; k < NB; ++k) {
        float2 a = Lt[lr][k];
        float2 u0 = Ut[k][lc0 + 0], u1 = Ut[k][lc0 + 1];
        float2 u2 = Ut[k][lc0 + 2], u3 = Ut[k][lc0 + 3];
        s0.x += a.x * u0.x - a.y * u0.y; s0.y += a.x * u0.y + a.y * u0.x;
        s1.x += a.x * u1.x - a.y * u1.y; s1.y += a.x * u1.y + a.y * u1.x;
        s2.x += a.x * u2.x - a.y * u2.y; s2.y += a.x * u2.y + a.y * u2.x;
        s3.x += a.x * u3.x - a.y * u3.y; s3.y += a.x * u3.y + a.y * u3.x;
    }
    size_t base = (size_t)(r0 + lr) * NE + c0 + lc0;
    float2 cc;
    cc = Am[base + 0]; cc.x -= s0.x; cc.y -= s0.y; Am[base + 0] = cc;
    cc = Am[base + 1]; cc.x -= s1.x; cc.y -= s1.y; Am[base + 1] = cc;
    cc = Am[base + 2]; cc.x -= s2.x; cc.y -= s2.y; Am[base + 2] = cc;
    cc = Am[base + 3]; cc.x -= s3.x; cc.y -= s3.y; Am[base + 3] = cc;
}

__global__ void finalize_k(const float* __restrict__ acc, float* __restrict__ out) {
    if (threadIdx.x == 0) {
        float ang = acc[3] + 3.14159265358979323846f * acc[4];
        ang -= 6.283185307179586f * rintf(ang * 0.15915494309189535f);
        out[0] = 0.5f * acc[2] + acc[0];
        out[1] = 0.5f * ang + acc[1];
    }
}

// ---------------- host launch ----------------
extern "C" void kernel_launch(void* const* d_in, const int* in_sizes, int n_in,
                              void* d_out, int out_size, void* d_ws, size_t ws_size,
                              hipStream_t stream) {
    (void)in_sizes; (void)n_in; (void)out_size;
    const float* el   = (const float*)d_in[0];
    const float* Win  = (const float*)d_in[1];
    const float* Wq   = (const float*)d_in[2];
    const float* bq   = (const float*)d_in[3];
    const float* Wk   = (const float*)d_in[4];
    const float* bk   = (const float*)d_in[5];
    const float* Wv   = (const float*)d_in[6];
    const float* bv   = (const float*)d_in[7];
    const float* Wo   = (const float*)d_in[8];
    const float* bo   = (const float*)d_in[9];
    const float* W1   = (const float*)d_in[10];
    const float* ln1s = (const float*)d_in[11];
    const float* ln1b = (const float*)d_in[12];
    const float* W2   = (const float*)d_in[13];
    const float* b2   = (const float*)d_in[14];
    const float* ln2s = (const float*)d_in[15];
    const float* ln2b = (const float*)d_in[16];
    const float* Wor  = (const float*)d_in[17];
    const float* Woi  = (const float*)d_in[18];

    char* wp = (char*)d_ws;
    auto alloc = [&](size_t b) {
        char* r = wp;
        wp += (b + 255) & ~(size_t)255;
        return r;
    };
    int*    ipb  = (int*)alloc((size_t)P_TOT * 4);
    int*    jpb  = (int*)alloc((size_t)P_TOT * 4);
    float2* porb = (float2*)alloc((size_t)P_TOT * 8);
    float2* Am   = (float2*)alloc((size_t)NE * NE * 8);
    float*  acc  = (float*)alloc(256);
    ushort* Wqkv_t = (ushort*)alloc((size_t)2 * 768 * 256 * 2);
    ushort* Woth_t = (ushort*)alloc((size_t)6 * 65536 * 2);
    ushort* Wf_t   = (ushort*)alloc((size_t)2 * 65536 * 2);
    float*  bfuse  = (float*)alloc((size_t)2 * 256 * 4);
    float*  bqkv = (float*)alloc((size_t)2 * 768 * 4);
    size_t fixed = (size_t)(wp - (char*)d_ws);

    // runtime chunk count: prefer 1 (biggest GEMM grids, fewest dispatches)
    int nchunk = 0, PCr = 0, MCr = 0;
    const int cands[3] = {1, 2, 3};
    for (int ci = 0; ci < 3; ++ci) {
        int pc = P_TOT / cands[ci];            // 32640 / 16320 / 10880 (all %64==0)
        size_t mc = (size_t)2 * pc;
        size_t var = 0;
        var += ((mc * 256 * 2 + 255) & ~(size_t)255);   // hb
        var += ((mc * 768 * 2 + 255) & ~(size_t)255);   // qkvb
        if (fixed + var <= ws_size) { nchunk = cands[ci]; PCr = pc; MCr = (int)mc; break; }
    }
    if (!nchunk) {
        zero_k<<<1, 64, 0, stream>>>((float*)d_out);
        return;
    }
    ushort* hb   = (ushort*)alloc((size_t)MCr * 256 * 2);
    ushort* qkvb = (ushort*)alloc((size_t)MCr * 768 * 2);
    int MTr = MCr / 128;

    prep_w_k<<<dim3(8, 8, 12), 256, 0, stream>>>(Wq, Wk, Wv, Wo, W1, W2, Wqkv_t, Woth_t);
    prep_b_k<<<2, 256, 0, stream>>>(bq, bk, bv, bqkv);
    fuse_w_k<<<dim3(8, 8, 2), 256, 0, stream>>>(Wo, W1, Wf_t);
    fuse_b_k<<<2, 256, 0, stream>>>(bo, W1, bfuse);
    idx_k<<<1, 256, 0, stream>>>(ipb, jpb);
    zero_k<<<1, 64, 0, stream>>>(acc);

    for (int c = 0; c < nchunk; ++c) {
        int P0 = c * PCr;
        embed_k<<<MCr / 4, 256, 0, stream>>>(el, Win, ipb, jpb, hb, P0);
        for (int l = 0; l < NL; ++l) {
            gemm_k<true, false><<<MTr * 6, 256, 0, stream>>>(
                hb, 256, Wqkv_t + (size_t)l * 768 * 256, bqkv + l * 768, nullptr, 0, qkvb, 768, 6);
            attn_k<<<PCr, 256, 0, stream>>>(qkvb);
            // hb = LN( o@Wf + bfuse + hb )
            gemm_ln_k<false><<<MTr, 512, 0, stream>>>(
                qkvb, 768, Wf_t + (size_t)l * 65536, bfuse + l * 256, hb,
                ln1s + l * 256, ln1b + l * 256, hb);
            // hb = LN( hb + tanh(hb@W2 + b2) )
            gemm_ln_k<true><<<MTr, 512, 0, stream>>>(
                hb, 256, Woth_t + (size_t)(l * 3 + 2) * 65536, b2 + l * 256, hb,
                ln2s + l * 256, ln2b + l * 256, hb);
        }
        orb_k<<<PCr / 4, 256, 0, stream>>>(hb, Wor, Woi, el, ipb, jpb, porb, P0);
    }
    assemble_k<<<NE, 256, 0, stream>>>(el, porb, Am, acc);

    for (int p = 0; p < NPANEL; ++p) {
        int k0 = p * NB;
        panel_k<<<1, 256, 0, stream>>>(Am, acc, k0);   // panel + fused trsm
        int m = NE - k0 - NB;
        if (m > 0) {
            dim3 ug(m / NB, m / NB);
            update_k<<<ug, 256, 0, stream>>>(Am, k0);
        }
    }
    finalize_k<<<1, 64, 0, stream>>>(acc, (float*)d_out);
}